// Round 14
// baseline (45.146 us; speedup 1.0000x reference)
//
#include <hip/hip_runtime.h>
#include <hip/hip_fp16.h>

// SSIM loss, fused separable 11x11 Gaussian conv + SSIM map + mean.
// Images: 32 x 1 x 512 x 512 fp32. Output: 1 fp32 scalar.
//
// R14 = R13 + circular h-buffer (42 slots) -> LDS 26 KB -> 6 blocks/CU.
// v-pass split in halves: out rows 0..31 need h rows 0..41 (slots=rows);
// out rows 32..63 need h rows 32..73 (rows 42..73 wrap to slots 0..31,
// which are dead after half A). h fits entirely in the dead raw-B region;
// sPK aliases raw-A (packed in place). Total LDS = raw region only.
//
// Stage 0: async global_load_lds stages fp32 tiles (all loads in flight)
// Prepass: pack (a,b)->half2 in place over raw-A; border zeros folded in
// Stage 2a/3a, 2b/3b: packed-fp16 h-conv -> circular h; v-conv -> SSIM
//   (4-field algebra: p=a+b, m=a-b; one v_pk_fma_f16 per tap, 2 fields)
// Kernel 2: deterministic tree reduce of 4096 partials -> scalar.

#define IMGW 512
#define IMGH 512
#define NIMG 32
#define TW 32
#define TH 64
#define IN_H 74        // TH + 10
#define IN_W 44        // LDS row stride (dwords); cols 0..41 used
#define NPIX (IN_H * IN_W)     // 3256
#define NCHUNK (IN_H * 11)     // 814 16B chunks per image tile
#define HSLOT 42       // circular h rows
#define NBX 16         // 512 / TW
#define NBY 8          // 512 / TH
#define NBLOCKS (NBX * NBY * NIMG)   // 4096

typedef __attribute__((address_space(1))) const uint32_t ga_u32;
typedef __attribute__((address_space(3))) uint32_t ls_u32;

__device__ __forceinline__ void load16_lds(const float* g, float* l) {
  __builtin_amdgcn_global_load_lds((ga_u32*)g, (ls_u32*)l, 16, 0, 0);
}

__device__ __forceinline__ __half2 h2_of(uint32_t w) {
  return __builtin_bit_cast(__half2, w);
}
__device__ __forceinline__ uint32_t u_of(__half2 h) {
  return __builtin_bit_cast(uint32_t, h);
}

__global__ __launch_bounds__(256, 6) void ssim_main(
    const float* __restrict__ img1, const float* __restrict__ img2,
    float* __restrict__ partial) {
  // Raw staging region: A tile fp32 [0..NPIX), B tile fp32 [NPIX..2*NPIX).
  // After prepass: A half = sPK (packed (a,b) half2); B half = circular h.
  __shared__ uint32_t uRaw[NPIX * 2];   // 26048 B
  __shared__ float sWave[4];
  uint32_t* sPK = uRaw;                 // packed tile, aliases raw-A
  uint32_t* hB = uRaw + NPIX;           // circular h: 42 slots x 64 u32
                                        //   slot*64 + c      -> (ca, cb)
                                        //   slot*64 + 32 + c -> (cp2, cm2)

  // Unnormalized Gaussian, 2*sigma^2 = 4 (faithful to reference).
  constexpr float g[11] = {0.0019304541f, 0.018315639f, 0.10539922f,
                           0.36787944f,   0.7788008f,   1.0f,
                           0.7788008f,    0.36787944f,  0.10539922f,
                           0.018315639f,  0.0019304541f};
  constexpr float C1v = 6.5025f;    // (0.01*255)^2
  constexpr float C2v = 58.5225f;   // (0.03*255)^2

  __half2 gh[11];
#pragma unroll
  for (int k = 0; k < 11; ++k) gh[k] = __float2half2_rn(g[k]);
  const __half2 c1m1 = __floats2half2_rn(1.0f, -1.0f);

  const int tid = threadIdx.x;
  const int bx = blockIdx.x;
  const int by = blockIdx.y;
  const int x0 = bx * TW - 5;
  const int y0 = by * TH - 5;
  const float* __restrict__ p1 = img1 + (size_t)blockIdx.z * (IMGW * IMGH);
  const float* __restrict__ p2 = img2 + (size_t)blockIdx.z * (IMGW * IMGH);
  float* sA = (float*)uRaw;
  float* sB = (float*)(uRaw + NPIX);

  // ---- Stage 0: async global->LDS staging, all loads in flight at once ----
#pragma unroll
  for (int i = 0; i < 4; ++i) {
    int ch = tid + 256 * i;
    if (ch < NCHUNK) {
      int r = ch / 11;
      int cg = ch - r * 11;
      int gy = y0 + r;
      int gx = x0 + 4 * cg;
      int gyc = min(max(gy, 0), IMGH - 1);
      int gxc = min(max(gx, 0), IMGW - 4);
      int src = gyc * IMGW + gxc;
      load16_lds(p1 + src, &sA[ch * 4]);
      load16_lds(p2 + src, &sB[ch * 4]);
    }
  }
  __syncthreads();   // drains vmcnt: staged data visible

  // ---- Prepass: pack (a,b)->half2 in place over raw-A (borders zeroed) ----
  const bool borderBlk =
      (bx == 0) || (bx == NBX - 1) || (by == 0) || (by == NBY - 1);
  if (!borderBlk) {
    for (int ch = tid; ch < NCHUNK; ch += 256) {
      float4 a = *(const float4*)&sA[ch * 4];
      float4 b = *(const float4*)&sB[ch * 4];
      uint4 w;
      w.x = u_of(__floats2half2_rn(a.x, b.x));
      w.y = u_of(__floats2half2_rn(a.y, b.y));
      w.z = u_of(__floats2half2_rn(a.z, b.z));
      w.w = u_of(__floats2half2_rn(a.w, b.w));
      *(uint4*)&sPK[ch * 4] = w;   // overwrites raw-A chunk ch (own thread)
    }
  } else {
    for (int ch = tid; ch < NCHUNK; ch += 256) {
      int r = ch / 11;
      int cg = ch - r * 11;
      int gy = y0 + r;
      int gx = x0 + 4 * cg;
      float4 a = *(const float4*)&sA[ch * 4];
      float4 b = *(const float4*)&sB[ch * 4];
      bool rowok = (gy >= 0) && (gy < IMGH);
      uint4 w;
      float av[4] = {a.x, a.y, a.z, a.w};
      float bv[4] = {b.x, b.y, b.z, b.w};
      uint32_t* wp = (uint32_t*)&w;
#pragma unroll
      for (int j = 0; j < 4; ++j) {
        bool ok = rowok && (gx + j >= 0) && (gx + j < IMGW);
        wp[j] = u_of(__floats2half2_rn(ok ? av[j] : 0.f, ok ? bv[j] : 0.f));
      }
      *(uint4*)&sPK[ch * 4] = w;
    }
  }
  __syncthreads();   // sPK ready; raw-B region now dead -> circular h

  // ---- Stage 2 worker: h rows [rowbase, rowbase+nrows) -> slots [0,nrows) ----
  auto stage2 = [&](int rowbase, int nrows) {
    for (int idx = tid; idx < nrows * 8; idx += 256) {
      int rr = idx >> 3;             // slot (= row - rowbase)
      int r = rowbase + rr;
      int c0 = (idx & 7) << 2;
      int base = r * IN_W + c0;      // 16B-aligned (c0 % 4 == 0)
      __half2 ab[14], pm2[14];
      {
        uint4 w0 = *(const uint4*)&sPK[base];
        uint4 w1 = *(const uint4*)&sPK[base + 4];
        uint4 w2 = *(const uint4*)&sPK[base + 8];
        uint2 w3 = *(const uint2*)&sPK[base + 12];
        uint32_t ws[14] = {w0.x, w0.y, w0.z, w0.w, w1.x, w1.y, w1.z,
                           w1.w, w2.x, w2.y, w2.z, w2.w, w3.x, w3.y};
#pragma unroll
        for (int k = 0; k < 14; ++k) {
          __half2 w = h2_of(ws[k]);
          ab[k] = w;
          __half2 t = __hfma2(__lowhigh2highlow(w), c1m1, w);  // (p, -m)
          pm2[k] = __hmul2(t, t);                              // (p2, m2)
        }
      }
      uint4 oab, opm;
#pragma unroll
      for (int o = 0; o < 4; ++o) {
        __half2 cab = __float2half2_rn(0.0f);
        __half2 cpm = __float2half2_rn(0.0f);
#pragma unroll
        for (int k = 0; k < 11; ++k) {
          cab = __hfma2(gh[k], ab[o + k], cab);
          cpm = __hfma2(gh[k], pm2[o + k], cpm);
        }
        ((uint32_t*)&oab)[o] = u_of(cab);
        ((uint32_t*)&opm)[o] = u_of(cpm);
      }
      *(uint4*)&hB[rr * 64 + c0] = oab;
      *(uint4*)&hB[rr * 64 + 32 + c0] = opm;
    }
  };

  // ---- Stage 3 worker: v-pass for 32 output rows starting at outbase ----
  float ssum = 0.f;
  auto stage3 = [&](int outbase) {
    const int c = tid & 31;
    const int r0 = outbase + ((tid >> 5) << 2);  // 4-row group
    __half2 m1[14], m2[14];
#pragma unroll
    for (int k = 0; k < 14; ++k) {
      int row = r0 + k;
      int slot = (row >= HSLOT) ? (row - HSLOT) : row;
      m1[k] = h2_of(hB[slot * 64 + c]);
      m2[k] = h2_of(hB[slot * 64 + 32 + c]);
    }
#pragma unroll
    for (int o = 0; o < 4; ++o) {
      __half2 s = __float2half2_rn(0.0f);
      __half2 t = __float2half2_rn(0.0f);
#pragma unroll
      for (int k = 0; k < 11; ++k) {
        s = __hfma2(gh[k], m1[o + k], s);
        t = __hfma2(gh[k], m2[o + k], t);
      }
      float m1f = __low2float(s);
      float m2f = __high2float(s);
      float qp = __low2float(t);
      float qm = __high2float(t);
      float sumsq = 0.5f * (qp + qm);   // E[a^2] + E[b^2]
      float eab = 0.25f * (qp - qm);    // E[ab]
      float m1s = m1f * m1f, m2s = m2f * m2f, m12 = m1f * m2f;
      float sg12 = eab - m12;
      float sgsum = sumsq - m1s - m2s;  // sigma1 + sigma2
      float num = (2.0f * m12 + C1v) * (2.0f * sg12 + C2v);
      float den = (m1s + m2s + C1v) * (sgsum + C2v);
      float r = num * __builtin_amdgcn_rcpf(den);
      // Guard singular pixels (den ~ +-0 -> inf; mixed-sign infs -> NaN).
      if (!__builtin_isfinite(r)) r = 0.0f;
      ssum += r;
    }
  };

  // half A: h rows 0..41 (slots 0..41), outputs 0..31
  stage2(0, HSLOT);
  __syncthreads();
  stage3(0);
  __syncthreads();     // protect slots 0..31 until half-A reads retire
  // half B: h rows 42..73 (slots 0..31), outputs 32..63
  stage2(HSLOT, IN_H - HSLOT);
  __syncthreads();
  stage3(32);

  // ---- block reduction (deterministic) ----
#pragma unroll
  for (int off = 32; off > 0; off >>= 1) ssum += __shfl_down(ssum, off, 64);
  if ((tid & 63) == 0) sWave[tid >> 6] = ssum;
  __syncthreads();
  if (tid == 0) {
    partial[(blockIdx.z * NBY + blockIdx.y) * NBX + blockIdx.x] =
        sWave[0] + sWave[1] + sWave[2] + sWave[3];
  }
}

__global__ __launch_bounds__(256) void ssim_reduce(
    const float* __restrict__ partial, float* __restrict__ out) {
  const int tid = threadIdx.x;
  float s = 0.f;
  for (int i = tid; i < NBLOCKS; i += 256) s += partial[i];
#pragma unroll
  for (int off = 32; off > 0; off >>= 1) s += __shfl_down(s, off, 64);
  __shared__ float sw[4];
  if ((tid & 63) == 0) sw[tid >> 6] = s;
  __syncthreads();
  if (tid == 0) {
    float tot = sw[0] + sw[1] + sw[2] + sw[3];
    // mean((1 - ssim)/2) = 0.5 * (1 - mean(ssim))
    float val = 0.5f * (1.0f - tot * (1.0f / (32.0f * 512.0f * 512.0f)));
    if (!__builtin_isfinite(val)) val = 0.0f;
    out[0] = val;
  }
}

extern "C" void kernel_launch(void* const* d_in, const int* in_sizes, int n_in,
                              void* d_out, int out_size, void* d_ws,
                              size_t ws_size, hipStream_t stream) {
  const float* img1 = (const float*)d_in[0];
  const float* img2 = (const float*)d_in[1];
  float* partial = (float*)d_ws;  // 4096 floats = 16 KB
  float* out = (float*)d_out;

  dim3 grid(NBX, NBY, NIMG);
  hipLaunchKernelGGL(ssim_main, grid, dim3(256), 0, stream, img1, img2,
                     partial);
  hipLaunchKernelGGL(ssim_reduce, dim3(1), dim3(256), 0, stream, partial, out);
}

// Round 15
// 40.937 us; speedup vs baseline: 1.1028x; 1.1028x over previous
//
#include <hip/hip_runtime.h>
#include <hip/hip_fp16.h>

// SSIM loss, fused separable 11x11 Gaussian conv + SSIM map + mean.
// Images: 32 x 1 x 512 x 512 fp32. Output: 1 fp32 scalar.
//
// R15 = R13 + counted-vmcnt staging pipeline (T4) + XCD-chunked swizzle (T1).
// DMA order: (A,B) per chunk-quarter i=0..3; ch = tid+256*i. After issue,
// s_waitcnt vmcnt(2) + raw s_barrier: every wave's first 4 DMA instrs are
// retired -> chunks [0,512) = px rows 0..46 resident; each wave's newest
// ~2 instrs (rows 47..73) stay IN FLIGHT under prepass-low + stage2-low.
// vmcnt(0) only at the high-half boundary. Barriers between LDS phases are
// raw s_barrier + lgkmcnt(0) (no vmcnt drain).
//
// Alias map (verified): hAB rows 0..41 -> uRaw[0..1344) (raw-A chunks<336,
// dead after prepass-low); hAB rows 42..73 -> uRaw[1344..2368) (chunks<592,
// dead by stage2-high). hPM ditto at uRaw[NPIX+...] over raw-B. prepass-high
// reads uRaw[2048..3256)+[NPIX+2048..) -- disjoint from stage2-low h writes.
//
// XCD swizzle: wgid=(bid&7)*512+(bid>>3) -> each XCD owns 4 contiguous
// images; halo re-reads hit that XCD's L2.
//
// Compute (R13): prepass packs (a,b)->half2 sPK; stage2 packed-fp16 h-conv
// (p=a+b,m=a-b; 1 v_pk_fma_f16/tap for 2 fields); stage3 v-conv + SSIM fp32.
// Kernel 2: deterministic tree reduce of 4096 partials.

#define IMGW 512
#define IMGH 512
#define NIMG 32
#define TW 32
#define TH 64
#define IN_H 74        // TH + 10
#define IN_W 44        // dword row stride; cols 0..41 used
#define NPIX (IN_H * IN_W)     // 3256
#define NCHUNK (IN_H * 11)     // 814 16B chunks per image tile
#define NBX 16
#define NBY 8
#define NBLOCKS (NBX * NBY * NIMG)   // 4096
#define LOWCH 512      // chunks resident after vmcnt(2) barrier (rows 0..46)
#define LOWROWS 42     // h rows computed in low phase (need px rows <= 41)

typedef __attribute__((address_space(1))) const uint32_t ga_u32;
typedef __attribute__((address_space(3))) uint32_t ls_u32;

__device__ __forceinline__ void load16_lds(const float* g, float* l) {
  __builtin_amdgcn_global_load_lds((ga_u32*)g, (ls_u32*)l, 16, 0, 0);
}
__device__ __forceinline__ __half2 h2_of(uint32_t w) {
  return __builtin_bit_cast(__half2, w);
}
__device__ __forceinline__ uint32_t u_of(__half2 h) {
  return __builtin_bit_cast(uint32_t, h);
}
__device__ __forceinline__ void lds_barrier() {
  asm volatile("s_waitcnt lgkmcnt(0)" ::: "memory");
  __builtin_amdgcn_s_barrier();
  __builtin_amdgcn_sched_barrier(0);
}

__global__ __launch_bounds__(256, 4) void ssim_main(
    const float* __restrict__ img1, const float* __restrict__ img2,
    float* __restrict__ partial) {
  __shared__ uint32_t uRaw[NPIX * 2];   // raw A | raw B; later h arrays alias
  __shared__ uint32_t sPK[NPIX];        // packed (a,b) half2
  __shared__ float sWave[4];
  float* sA = (float*)uRaw;
  float* sB = (float*)(uRaw + NPIX);
  uint32_t* hAB = uRaw;                 // [74][32], rows absolute
  uint32_t* hPM = uRaw + NPIX;          // [74][32]

  // Unnormalized Gaussian, 2*sigma^2 = 4 (faithful to reference).
  constexpr float g[11] = {0.0019304541f, 0.018315639f, 0.10539922f,
                           0.36787944f,   0.7788008f,   1.0f,
                           0.7788008f,    0.36787944f,  0.10539922f,
                           0.018315639f,  0.0019304541f};
  constexpr float C1v = 6.5025f;    // (0.01*255)^2
  constexpr float C2v = 58.5225f;   // (0.03*255)^2

  __half2 gh[11];
#pragma unroll
  for (int k = 0; k < 11; ++k) gh[k] = __float2half2_rn(g[k]);
  const __half2 c1m1 = __floats2half2_rn(1.0f, -1.0f);

  const int tid = threadIdx.x;
  // XCD-chunked swizzle: each of 8 XCDs gets 512 consecutive tiles.
  const int bid = blockIdx.x;
  const int wgid = (bid & 7) * (NBLOCKS / 8) + (bid >> 3);
  const int img = wgid >> 7;            // 128 tiles per image
  const int by = (wgid >> 4) & 7;
  const int bx = wgid & 15;
  const int x0 = bx * TW - 5;
  const int y0 = by * TH - 5;
  const float* __restrict__ p1 = img1 + (size_t)img * (IMGW * IMGH);
  const float* __restrict__ p2 = img2 + (size_t)img * (IMGW * IMGH);
  const bool borderBlk =
      (bx == 0) || (bx == NBX - 1) || (by == 0) || (by == NBY - 1);

  // ---- Stage 0: issue ALL DMA; order (A,B) per quarter i=0..3 ----
#pragma unroll
  for (int i = 0; i < 4; ++i) {
    int ch = tid + 256 * i;
    if (ch < NCHUNK) {
      int r = ch / 11;
      int cg = ch - r * 11;
      int gy = y0 + r;
      int gx = x0 + 4 * cg;
      int gyc = min(max(gy, 0), IMGH - 1);
      int gxc = min(max(gx, 0), IMGW - 4);
      int src = gyc * IMGW + gxc;
      load16_lds(p1 + src, &sA[ch * 4]);
      load16_lds(p2 + src, &sB[ch * 4]);
    }
  }
  // Counted wait: every wave (waves 1-3 issued 6 instrs, wave 0 issued 8)
  // has its i=0,1 (A,B) retired at vmcnt(2) -> chunks [0,512) resident.
  asm volatile("s_waitcnt vmcnt(2)" ::: "memory");
  __builtin_amdgcn_s_barrier();
  __builtin_amdgcn_sched_barrier(0);

  // ---- prepass worker: pack (a,b)->half2 into sPK for ch in [c0,c1) ----
  auto prepass = [&](int cbeg, int cend) {
    if (!borderBlk) {
      for (int ch = cbeg + tid; ch < cend; ch += 256) {
        float4 a = *(const float4*)&sA[ch * 4];
        float4 b = *(const float4*)&sB[ch * 4];
        uint4 w;
        w.x = u_of(__floats2half2_rn(a.x, b.x));
        w.y = u_of(__floats2half2_rn(a.y, b.y));
        w.z = u_of(__floats2half2_rn(a.z, b.z));
        w.w = u_of(__floats2half2_rn(a.w, b.w));
        *(uint4*)&sPK[ch * 4] = w;
      }
    } else {
      for (int ch = cbeg + tid; ch < cend; ch += 256) {
        int r = ch / 11;
        int cg = ch - r * 11;
        int gy = y0 + r;
        int gx = x0 + 4 * cg;
        float4 a = *(const float4*)&sA[ch * 4];
        float4 b = *(const float4*)&sB[ch * 4];
        bool rowok = (gy >= 0) && (gy < IMGH);
        uint4 w;
        float av[4] = {a.x, a.y, a.z, a.w};
        float bv[4] = {b.x, b.y, b.z, b.w};
        uint32_t* wp = (uint32_t*)&w;
#pragma unroll
        for (int j = 0; j < 4; ++j) {
          bool ok = rowok && (gx + j >= 0) && (gx + j < IMGW);
          wp[j] = u_of(__floats2half2_rn(ok ? av[j] : 0.f, ok ? bv[j] : 0.f));
        }
        *(uint4*)&sPK[ch * 4] = w;
      }
    }
  };

  // ---- stage2 worker: h rows [rowbase, rowbase+nrows) ----
  auto stage2 = [&](int rowbase, int nrows) {
    for (int idx = tid; idx < nrows * 8; idx += 256) {
      int r = rowbase + (idx >> 3);
      int c0 = (idx & 7) << 2;
      int base = r * IN_W + c0;
      __half2 ab[14], pm2[14];
      {
        uint4 w0 = *(const uint4*)&sPK[base];
        uint4 w1 = *(const uint4*)&sPK[base + 4];
        uint4 w2 = *(const uint4*)&sPK[base + 8];
        uint2 w3 = *(const uint2*)&sPK[base + 12];
        uint32_t ws[14] = {w0.x, w0.y, w0.z, w0.w, w1.x, w1.y, w1.z,
                           w1.w, w2.x, w2.y, w2.z, w2.w, w3.x, w3.y};
#pragma unroll
        for (int k = 0; k < 14; ++k) {
          __half2 w = h2_of(ws[k]);
          ab[k] = w;
          __half2 t = __hfma2(__lowhigh2highlow(w), c1m1, w);  // (p, -m)
          pm2[k] = __hmul2(t, t);                              // (p2, m2)
        }
      }
      uint4 oab, opm;
#pragma unroll
      for (int o = 0; o < 4; ++o) {
        __half2 cab = __float2half2_rn(0.0f);
        __half2 cpm = __float2half2_rn(0.0f);
#pragma unroll
        for (int k = 0; k < 11; ++k) {
          cab = __hfma2(gh[k], ab[o + k], cab);
          cpm = __hfma2(gh[k], pm2[o + k], cpm);
        }
        ((uint32_t*)&oab)[o] = u_of(cab);
        ((uint32_t*)&opm)[o] = u_of(cpm);
      }
      *(uint4*)&hAB[r * 32 + c0] = oab;
      *(uint4*)&hPM[r * 32 + c0] = opm;
    }
  };

  // ---- pipelined phases ----
  prepass(0, LOWCH);        // px rows 0..46 (chunks 0..511)
  lds_barrier();
  stage2(0, LOWROWS);       // h rows 0..41 (needs px rows <= 41 only)
  asm volatile("s_waitcnt vmcnt(0) lgkmcnt(0)" ::: "memory");
  __builtin_amdgcn_s_barrier();
  __builtin_amdgcn_sched_barrier(0);
  prepass(LOWCH, NCHUNK);   // px rows 46..73
  lds_barrier();
  stage2(LOWROWS, IN_H - LOWROWS);  // h rows 42..73
  lds_barrier();

  // ---- Stage 3: vertical pass, packed fp16, 8 output rows per thread ----
  const int c = tid & 31;
  const int r0 = (tid >> 5) << 3;  // 0..56
  __half2 mAB[8], mPM[8];
  {
    __half2 m1[18], m2[18];
#pragma unroll
    for (int k = 0; k < 18; ++k) {
      m1[k] = h2_of(hAB[(r0 + k) * 32 + c]);
      m2[k] = h2_of(hPM[(r0 + k) * 32 + c]);
    }
#pragma unroll
    for (int o = 0; o < 8; ++o) {
      __half2 s = __float2half2_rn(0.0f);
      __half2 t = __float2half2_rn(0.0f);
#pragma unroll
      for (int k = 0; k < 11; ++k) {
        s = __hfma2(gh[k], m1[o + k], s);
        t = __hfma2(gh[k], m2[o + k], t);
      }
      mAB[o] = s; mPM[o] = t;
    }
  }

  float ssum = 0.f;
#pragma unroll
  for (int o = 0; o < 8; ++o) {
    float m1 = __low2float(mAB[o]);
    float m2 = __high2float(mAB[o]);
    float qp = __low2float(mPM[o]);
    float qm = __high2float(mPM[o]);
    float sumsq = 0.5f * (qp + qm);   // E[a^2] + E[b^2]
    float eab = 0.25f * (qp - qm);    // E[ab]
    float m1s = m1 * m1, m2s = m2 * m2, m12 = m1 * m2;
    float sg12 = eab - m12;
    float sgsum = sumsq - m1s - m2s;  // sigma1 + sigma2
    float num = (2.0f * m12 + C1v) * (2.0f * sg12 + C2v);
    float den = (m1s + m2s + C1v) * (sgsum + C2v);
    float r = num * __builtin_amdgcn_rcpf(den);
    // Guard singular pixels (den ~ +-0 -> inf; mixed-sign infs -> NaN).
    if (!__builtin_isfinite(r)) r = 0.0f;
    ssum += r;
  }

  // ---- block reduction (deterministic) ----
#pragma unroll
  for (int off = 32; off > 0; off >>= 1) ssum += __shfl_down(ssum, off, 64);
  if ((tid & 63) == 0) sWave[tid >> 6] = ssum;
  __syncthreads();
  if (tid == 0) {
    partial[wgid] = sWave[0] + sWave[1] + sWave[2] + sWave[3];
  }
}

__global__ __launch_bounds__(256) void ssim_reduce(
    const float* __restrict__ partial, float* __restrict__ out) {
  const int tid = threadIdx.x;
  float s = 0.f;
  for (int i = tid; i < NBLOCKS; i += 256) s += partial[i];
#pragma unroll
  for (int off = 32; off > 0; off >>= 1) s += __shfl_down(s, off, 64);
  __shared__ float sw[4];
  if ((tid & 63) == 0) sw[tid >> 6] = s;
  __syncthreads();
  if (tid == 0) {
    float tot = sw[0] + sw[1] + sw[2] + sw[3];
    // mean((1 - ssim)/2) = 0.5 * (1 - mean(ssim))
    float val = 0.5f * (1.0f - tot * (1.0f / (32.0f * 512.0f * 512.0f)));
    if (!__builtin_isfinite(val)) val = 0.0f;
    out[0] = val;
  }
}

extern "C" void kernel_launch(void* const* d_in, const int* in_sizes, int n_in,
                              void* d_out, int out_size, void* d_ws,
                              size_t ws_size, hipStream_t stream) {
  const float* img1 = (const float*)d_in[0];
  const float* img2 = (const float*)d_in[1];
  float* partial = (float*)d_ws;  // 4096 floats = 16 KB
  float* out = (float*)d_out;

  hipLaunchKernelGGL(ssim_main, dim3(NBLOCKS), dim3(256), 0, stream, img1,
                     img2, partial);
  hipLaunchKernelGGL(ssim_reduce, dim3(1), dim3(256), 0, stream, partial, out);
}

// Round 16
// 39.777 us; speedup vs baseline: 1.1350x; 1.0292x over previous
//
#include <hip/hip_runtime.h>
#include <hip/hip_fp16.h>

// SSIM loss, fused separable 11x11 Gaussian conv + SSIM map + mean.
// Images: 32 x 1 x 512 x 512 fp32. Output: 1 fp32 scalar.
//
// R16 = R15 + instruction diet:
//  - stage2 8-wide tasks (296/block): read amp 3.5x->2.25x, -15% instrs
//  - stage3: col-pair b64 reads (h stride 36 -> bank-disjoint row groups),
//    rolling conv accumulation, packed-fp16 epilogue (2 outputs per pk op)
//    with 1/8 scale folded into stage-3 weights (fp16-safe ranges), f32
//    rcp finish + isfinite guard.
//  - kept: async global_load_lds staging, counted vmcnt(2) split pipeline
//    (LOWROWS=46), prepass pack + LDS aliasing, XCD-chunked swizzle.
//
// Alias map (stride-36 h): hAB = uRaw[0..2664) over raw-A; stage2-low
// writes rows 0..45 -> dwords < 1656 < 2048 (raw-A chunks 0..511, dead
// after prepass-low). prepass-high reads dwords 2048..3255 - disjoint.
// hPM ditto over raw-B at uRaw+NPIX.

#define IMGW 512
#define IMGH 512
#define NIMG 32
#define TW 32
#define TH 64
#define IN_H 74        // TH + 10
#define IN_W 44        // sPK row stride (dwords); cols 0..41 used
#define HSTR 36        // h row stride (dwords)
#define NPIX (IN_H * IN_W)     // 3256
#define NCHUNK (IN_H * 11)     // 814 16B chunks per image tile
#define NBX 16
#define NBY 8
#define NBLOCKS (NBX * NBY * NIMG)   // 4096
#define LOWCH 512      // chunks resident after vmcnt(2) barrier
#define LOWROWS 46     // h rows in low phase (need px rows <= 45, ch <= 505)

typedef __attribute__((address_space(1))) const uint32_t ga_u32;
typedef __attribute__((address_space(3))) uint32_t ls_u32;

__device__ __forceinline__ void load16_lds(const float* g, float* l) {
  __builtin_amdgcn_global_load_lds((ga_u32*)g, (ls_u32*)l, 16, 0, 0);
}
__device__ __forceinline__ __half2 h2_of(uint32_t w) {
  return __builtin_bit_cast(__half2, w);
}
__device__ __forceinline__ uint32_t u_of(__half2 h) {
  return __builtin_bit_cast(uint32_t, h);
}
__device__ __forceinline__ void lds_barrier() {
  asm volatile("s_waitcnt lgkmcnt(0)" ::: "memory");
  __builtin_amdgcn_s_barrier();
  __builtin_amdgcn_sched_barrier(0);
}

__global__ __launch_bounds__(256, 4) void ssim_main(
    const float* __restrict__ img1, const float* __restrict__ img2,
    float* __restrict__ partial) {
  __shared__ uint32_t uRaw[NPIX * 2];   // raw A | raw B; h arrays alias
  __shared__ uint32_t sPK[NPIX];        // packed (a,b) half2
  __shared__ float sWave[4];
  float* sA = (float*)uRaw;
  float* sB = (float*)(uRaw + NPIX);
  uint32_t* hAB = uRaw;                 // [74][HSTR], rows absolute
  uint32_t* hPM = uRaw + NPIX;          // [74][HSTR]

  // Unnormalized Gaussian, 2*sigma^2 = 4 (faithful to reference).
  constexpr float g[11] = {0.0019304541f, 0.018315639f, 0.10539922f,
                           0.36787944f,   0.7788008f,   1.0f,
                           0.7788008f,    0.36787944f,  0.10539922f,
                           0.018315639f,  0.0019304541f};

  __half2 gh[11], gh8[11];
#pragma unroll
  for (int k = 0; k < 11; ++k) {
    gh[k] = __float2half2_rn(g[k]);
    gh8[k] = __float2half2_rn(g[k] * 0.125f);   // stage-3 scale fold
  }
  const __half2 c1m1 = __floats2half2_rn(1.0f, -1.0f);
  const __half2 kQS = __float2half2_rn(0.0625f);    // sumsq scale
  const __half2 kQD = __float2half2_rn(0.03125f);   // eab scale
  const __half2 C1s = __float2half2_rn(6.5025f / 64.0f);
  const __half2 C2s = __float2half2_rn(58.5225f / 64.0f);
  const __half2 htwo = __float2half2_rn(2.0f);

  const int tid = threadIdx.x;
  // XCD-chunked swizzle: each of 8 XCDs gets 512 consecutive tiles.
  const int bid = blockIdx.x;
  const int wgid = (bid & 7) * (NBLOCKS / 8) + (bid >> 3);
  const int img = wgid >> 7;
  const int by = (wgid >> 4) & 7;
  const int bx = wgid & 15;
  const int x0 = bx * TW - 5;
  const int y0 = by * TH - 5;
  const float* __restrict__ p1 = img1 + (size_t)img * (IMGW * IMGH);
  const float* __restrict__ p2 = img2 + (size_t)img * (IMGW * IMGH);
  const bool borderBlk =
      (bx == 0) || (bx == NBX - 1) || (by == 0) || (by == NBY - 1);

  // ---- Stage 0: issue ALL DMA; order (A,B) per quarter i=0..3 ----
#pragma unroll
  for (int i = 0; i < 4; ++i) {
    int ch = tid + 256 * i;
    if (ch < NCHUNK) {
      int r = ch / 11;
      int cg = ch - r * 11;
      int gy = y0 + r;
      int gx = x0 + 4 * cg;
      int gyc = min(max(gy, 0), IMGH - 1);
      int gxc = min(max(gx, 0), IMGW - 4);
      int src = gyc * IMGW + gxc;
      load16_lds(p1 + src, &sA[ch * 4]);
      load16_lds(p2 + src, &sB[ch * 4]);
    }
  }
  // Counted wait: all waves' first two (A,B) pairs retired -> chunks [0,512).
  asm volatile("s_waitcnt vmcnt(2)" ::: "memory");
  __builtin_amdgcn_s_barrier();
  __builtin_amdgcn_sched_barrier(0);

  // ---- prepass worker: pack (a,b)->half2 into sPK for ch in [cbeg,cend) ----
  auto prepass = [&](int cbeg, int cend) {
    if (!borderBlk) {
      for (int ch = cbeg + tid; ch < cend; ch += 256) {
        float4 a = *(const float4*)&sA[ch * 4];
        float4 b = *(const float4*)&sB[ch * 4];
        uint4 w;
        w.x = u_of(__floats2half2_rn(a.x, b.x));
        w.y = u_of(__floats2half2_rn(a.y, b.y));
        w.z = u_of(__floats2half2_rn(a.z, b.z));
        w.w = u_of(__floats2half2_rn(a.w, b.w));
        *(uint4*)&sPK[ch * 4] = w;
      }
    } else {
      for (int ch = cbeg + tid; ch < cend; ch += 256) {
        int r = ch / 11;
        int cg = ch - r * 11;
        int gy = y0 + r;
        int gx = x0 + 4 * cg;
        float4 a = *(const float4*)&sA[ch * 4];
        float4 b = *(const float4*)&sB[ch * 4];
        bool rowok = (gy >= 0) && (gy < IMGH);
        uint4 w;
        float av[4] = {a.x, a.y, a.z, a.w};
        float bv[4] = {b.x, b.y, b.z, b.w};
        uint32_t* wp = (uint32_t*)&w;
#pragma unroll
        for (int j = 0; j < 4; ++j) {
          bool ok = rowok && (gx + j >= 0) && (gx + j < IMGW);
          wp[j] = u_of(__floats2half2_rn(ok ? av[j] : 0.f, ok ? bv[j] : 0.f));
        }
        *(uint4*)&sPK[ch * 4] = w;
      }
    }
  };

  // ---- stage2 worker: 8-wide tasks; h rows [rowbase, rowbase+nrows) ----
  auto stage2 = [&](int rowbase, int nrows) {
    for (int idx = tid; idx < nrows * 4; idx += 256) {
      int r = rowbase + (idx >> 2);
      int c0 = (idx & 3) << 3;        // 0,8,16,24
      int base = r * IN_W + c0;       // 16B-aligned
      __half2 ab[18], pm2[18];
      {
        uint4 w0 = *(const uint4*)&sPK[base];
        uint4 w1 = *(const uint4*)&sPK[base + 4];
        uint4 w2 = *(const uint4*)&sPK[base + 8];
        uint4 w3 = *(const uint4*)&sPK[base + 12];
        uint2 w4 = *(const uint2*)&sPK[base + 16];
        uint32_t ws[18] = {w0.x, w0.y, w0.z, w0.w, w1.x, w1.y, w1.z, w1.w,
                           w2.x, w2.y, w2.z, w2.w, w3.x, w3.y, w3.z, w3.w,
                           w4.x, w4.y};
#pragma unroll
        for (int k = 0; k < 18; ++k) {
          __half2 w = h2_of(ws[k]);
          ab[k] = w;
          __half2 t = __hfma2(__lowhigh2highlow(w), c1m1, w);  // (p, -m)
          pm2[k] = __hmul2(t, t);                              // (p2, m2)
        }
      }
      uint32_t oab[8], opm[8];
#pragma unroll
      for (int o = 0; o < 8; ++o) {
        __half2 cab = __float2half2_rn(0.0f);
        __half2 cpm = __float2half2_rn(0.0f);
#pragma unroll
        for (int k = 0; k < 11; ++k) {
          cab = __hfma2(gh[k], ab[o + k], cab);
          cpm = __hfma2(gh[k], pm2[o + k], cpm);
        }
        oab[o] = u_of(cab);
        opm[o] = u_of(cpm);
      }
      int hb = r * HSTR + c0;
      *(uint4*)&hAB[hb] = make_uint4(oab[0], oab[1], oab[2], oab[3]);
      *(uint4*)&hAB[hb + 4] = make_uint4(oab[4], oab[5], oab[6], oab[7]);
      *(uint4*)&hPM[hb] = make_uint4(opm[0], opm[1], opm[2], opm[3]);
      *(uint4*)&hPM[hb + 4] = make_uint4(opm[4], opm[5], opm[6], opm[7]);
    }
  };

  // ---- pipelined phases ----
  prepass(0, LOWCH);
  lds_barrier();
  stage2(0, LOWROWS);
  asm volatile("s_waitcnt vmcnt(0) lgkmcnt(0)" ::: "memory");
  __builtin_amdgcn_s_barrier();
  __builtin_amdgcn_sched_barrier(0);
  prepass(LOWCH, NCHUNK);
  lds_barrier();
  stage2(LOWROWS, IN_H - LOWROWS);
  lds_barrier();

  // ---- Stage 3: col-pair v-pass, rolling accumulation, pk epilogue ----
  // thread: cp = tid&15 -> cols {2cp, 2cp+1}; rg = tid>>4 -> rows 4rg..4rg+3
  const int cp = tid & 15;
  const int rg = tid >> 4;
  const int r0 = rg << 2;
  __half2 aAB0[4], aAB1[4], aPM0[4], aPM1[4];
#pragma unroll
  for (int o = 0; o < 4; ++o) {
    aAB0[o] = __float2half2_rn(0.f);
    aAB1[o] = __float2half2_rn(0.f);
    aPM0[o] = __float2half2_rn(0.f);
    aPM1[o] = __float2half2_rn(0.f);
  }
#pragma unroll
  for (int k = 0; k < 14; ++k) {
    int row = r0 + k;
    uint2 ab = *(const uint2*)&hAB[row * HSTR + 2 * cp];
    uint2 pm = *(const uint2*)&hPM[row * HSTR + 2 * cp];
#pragma unroll
    for (int o = 0; o < 4; ++o) {
      if (k - o >= 0 && k - o <= 10) {
        aAB0[o] = __hfma2(gh8[k - o], h2_of(ab.x), aAB0[o]);
        aAB1[o] = __hfma2(gh8[k - o], h2_of(ab.y), aAB1[o]);
        aPM0[o] = __hfma2(gh8[k - o], h2_of(pm.x), aPM0[o]);
        aPM1[o] = __hfma2(gh8[k - o], h2_of(pm.y), aPM1[o]);
      }
    }
  }

  float ssum = 0.f;
#pragma unroll
  for (int o = 0; o < 4; ++o) {
    uint32_t uab0 = u_of(aAB0[o]), uab1 = u_of(aAB1[o]);
    uint32_t upm0 = u_of(aPM0[o]), upm1 = u_of(aPM1[o]);
    // pair across the two columns: lo-halves and hi-halves
    __half2 M1 = h2_of(__builtin_amdgcn_perm(uab1, uab0, 0x05040100));
    __half2 M2 = h2_of(__builtin_amdgcn_perm(uab1, uab0, 0x07060302));
    __half2 QP = h2_of(__builtin_amdgcn_perm(upm1, upm0, 0x05040100));
    __half2 QM = h2_of(__builtin_amdgcn_perm(upm1, upm0, 0x07060302));
    __half2 m12 = __hmul2(M1, M2);
    __half2 s1q = __hmul2(M1, M1);
    __half2 s2q = __hmul2(M2, M2);
    __half2 sumsq = __hmul2(__hadd2(QP, QM), kQS);
    __half2 eab = __hmul2(__hsub2(QP, QM), kQD);
    __half2 sg12 = __hsub2(eab, m12);
    __half2 sgsum = __hsub2(__hsub2(sumsq, s1q), s2q);
    __half2 numA = __hfma2(m12, htwo, C1s);
    __half2 numB = __hfma2(sg12, htwo, C2s);
    __half2 num = __hmul2(numA, numB);
    __half2 denA = __hadd2(__hadd2(s1q, s2q), C1s);
    __half2 denB = __hadd2(sgsum, C2s);
    __half2 den = __hmul2(denA, denB);
    float nlo = __low2float(num), nhi = __high2float(num);
    float dlo = __low2float(den), dhi = __high2float(den);
    float ra = nlo * __builtin_amdgcn_rcpf(dlo);
    float rb = nhi * __builtin_amdgcn_rcpf(dhi);
    if (!__builtin_isfinite(ra)) ra = 0.f;
    if (!__builtin_isfinite(rb)) rb = 0.f;
    ssum += ra + rb;
  }

  // ---- block reduction (deterministic) ----
#pragma unroll
  for (int off = 32; off > 0; off >>= 1) ssum += __shfl_down(ssum, off, 64);
  if ((tid & 63) == 0) sWave[tid >> 6] = ssum;
  __syncthreads();
  if (tid == 0) {
    partial[wgid] = sWave[0] + sWave[1] + sWave[2] + sWave[3];
  }
}

__global__ __launch_bounds__(256) void ssim_reduce(
    const float* __restrict__ partial, float* __restrict__ out) {
  const int tid = threadIdx.x;
  float s = 0.f;
  for (int i = tid; i < NBLOCKS; i += 256) s += partial[i];
#pragma unroll
  for (int off = 32; off > 0; off >>= 1) s += __shfl_down(s, off, 64);
  __shared__ float sw[4];
  if ((tid & 63) == 0) sw[tid >> 6] = s;
  __syncthreads();
  if (tid == 0) {
    float tot = sw[0] + sw[1] + sw[2] + sw[3];
    // mean((1 - ssim)/2) = 0.5 * (1 - mean(ssim))
    float val = 0.5f * (1.0f - tot * (1.0f / (32.0f * 512.0f * 512.0f)));
    if (!__builtin_isfinite(val)) val = 0.0f;
    out[0] = val;
  }
}

extern "C" void kernel_launch(void* const* d_in, const int* in_sizes, int n_in,
                              void* d_out, int out_size, void* d_ws,
                              size_t ws_size, hipStream_t stream) {
  const float* img1 = (const float*)d_in[0];
  const float* img2 = (const float*)d_in[1];
  float* partial = (float*)d_ws;  // 4096 floats = 16 KB
  float* out = (float*)d_out;

  hipLaunchKernelGGL(ssim_main, dim3(NBLOCKS), dim3(256), 0, stream, img1,
                     img2, partial);
  hipLaunchKernelGGL(ssim_reduce, dim3(1), dim3(256), 0, stream, partial, out);
}